// Round 2
// baseline (377.089 us; speedup 1.0000x reference)
//
#include <hip/hip_runtime.h>
#include <hip/hip_bf16.h>
#include <stdint.h>

// GNN 2-layer: out = relu(h@Ws1^T + A@(h@Wn1^T)), h = relu(x@Ws0^T + (A@x)@Wn0^T)
// A = [8192][8192] int32 {0,1}. Floor: streaming A twice (~136MB HBM + L3 hits per pass).

typedef __attribute__((ext_vector_type(8))) short bf16x8;   // 8 bf16 in 4 VGPRs
typedef __attribute__((ext_vector_type(4))) float f32x4;

union U4 { uint4 u; int4 i; bf16x8 b; };

__device__ inline f32x4 mfma16(bf16x8 a, bf16x8 b, f32x4 c) {
    return __builtin_amdgcn_mfma_f32_16x16x32_bf16(a, b, c, 0, 0, 0);
}

__device__ inline unsigned short f2bf(float f) {
    union { float f; unsigned int u; } v; v.f = f;
    unsigned int u = v.u;
    return (unsigned short)((u + 0x7FFFu + ((u >> 16) & 1u)) >> 16);  // RNE
}

// ---------------------------------------------------------------------------
// Kernel 0: convert x -> x_bf16 [8192][128] and xT_bf16 [128][8192];
//           convert 4 weight matrices -> wcat bf16 (ws0|wn0|ws1|wn1).
// ---------------------------------------------------------------------------
__global__ __launch_bounds__(256) void convert_kernel(
    const float* __restrict__ x,
    const float* __restrict__ w0, const float* __restrict__ w1,
    const float* __restrict__ w2, const float* __restrict__ w3,
    unsigned short* __restrict__ xb, unsigned short* __restrict__ xT,
    unsigned short* __restrict__ wcat)
{
    const int bid = blockIdx.x, t = threadIdx.x;
    if (bid < 128) {
        // 64 rows of x per block: write x_bf16 linear + xT via LDS transpose
        __shared__ unsigned short XT[128][72];   // padded rows (144B, 16B-aligned)
        const int base = bid * 8192;             // 64 rows * 128 cols
        #pragma unroll
        for (int i = 0; i < 32; ++i) {
            int off = i * 256 + t;
            unsigned short b = f2bf(x[base + off]);
            xb[base + off] = b;
            XT[off & 127][off >> 7] = b;         // [col][local row]
        }
        __syncthreads();
        const int c = t >> 1, half = t & 1;      // c: 0..127, half selects 32 shorts
        const uint4* src = (const uint4*)&XT[c][half * 32];
        uint4* dst = (uint4*)(xT + c * 8192 + bid * 64 + half * 32);
        dst[0] = src[0]; dst[1] = src[1]; dst[2] = src[2]; dst[3] = src[3];
    } else {
        // weights: 131072 elements over 8 blocks
        int w = (bid - 128) * 16384 + t;
        #pragma unroll
        for (int i = 0; i < 64; ++i, w += 256) {
            float v;
            if      (w < 32768)  v = w0[w];
            else if (w < 65536)  v = w1[w - 32768];
            else if (w < 98304)  v = w2[w - 65536];
            else                 v = w3[w - 98304];
            wcat[w] = f2bf(v);
        }
    }
}

// ---------------------------------------------------------------------------
// Kernel 1 (used twice): C[8192][128] += A_chunk @ B, B given transposed as
// BT [128][8192] bf16. Split-K = 8, grid = 128*8 = 1024 blocks, 4 waves/block,
// each wave owns 16 rows independently. NO LDS: the MFMA A-fragment layout
// (row = lane&15, k = (lane>>4)*8 + 0..7) is directly 2x dwordx4 from
// row-major A. Register pipeline: A prefetch depth 2 (HBM/L3 latency),
// B prefetch depth 1 (L2-hot, BT is 2MB). MFMA runs with 10 loads in flight.
// ---------------------------------------------------------------------------
__global__ __launch_bounds__(256) void neigh_gemm(
    const int* __restrict__ A, const __hip_bfloat16* __restrict__ BT,
    float* __restrict__ C)
{
    const int t    = threadIdx.x;
    const int lane = t & 63;
    const int wave = t >> 6;
    const int bid  = blockIdx.x;
    const int mbase = (bid >> 3) << 6;           // 0..8128 step 64
    const int kbase = (bid & 7) << 10;           // k-chunk of 1024

    const int frow  = mbase + (wave << 4) + (lane & 15);
    const int kslot = (lane >> 4) << 3;          // 0,8,16,24

    const int* gA = A + frow * 8192 + kbase + kslot;
    const unsigned short* gB =
        (const unsigned short*)BT + (lane & 15) * 8192 + kbase + kslot;

    f32x4 acc[8];
    #pragma unroll
    for (int n = 0; n < 8; ++n) acc[n] = (f32x4){0.f, 0.f, 0.f, 0.f};

#define CVT_A(af, lo, hi)                                      \
    af.u.x = (unsigned)(lo.x | (lo.y << 16)) * 0x3F80u;        \
    af.u.y = (unsigned)(lo.z | (lo.w << 16)) * 0x3F80u;        \
    af.u.z = (unsigned)(hi.x | (hi.y << 16)) * 0x3F80u;        \
    af.u.w = (unsigned)(hi.z | (hi.w << 16)) * 0x3F80u;

    // pipeline registers
    int4 a0lo, a0hi, a1lo, a1hi;
    U4 b0[8];

    // prologue: A for steps 0,1; B for step 0
    a0lo = *(const int4*)(gA);
    a0hi = *(const int4*)(gA + 4);
    a1lo = *(const int4*)(gA + 32);
    a1hi = *(const int4*)(gA + 36);
    #pragma unroll
    for (int n = 0; n < 8; ++n) b0[n].u = *(const uint4*)(gB + n * (16 * 8192));

    // main loop: guard-free prefetch for it in [0,30)
    #pragma unroll 2
    for (int it = 0; it < 30; ++it) {
        U4 b1[8];
        const unsigned short* gBn = gB + (it + 1) * 32;
        #pragma unroll
        for (int n = 0; n < 8; ++n) b1[n].u = *(const uint4*)(gBn + n * (16 * 8192));
        int4 a2lo = *(const int4*)(gA + (it + 2) * 32);
        int4 a2hi = *(const int4*)(gA + (it + 2) * 32 + 4);

        U4 af; CVT_A(af, a0lo, a0hi);
        #pragma unroll
        for (int n = 0; n < 8; ++n) acc[n] = mfma16(af.b, b0[n].b, acc[n]);

        a0lo = a1lo; a0hi = a1hi; a1lo = a2lo; a1hi = a2hi;
        #pragma unroll
        for (int n = 0; n < 8; ++n) b0[n] = b1[n];
    }
    // it = 30: prefetch B only
    {
        U4 b1[8];
        const unsigned short* gBn = gB + 31 * 32;
        #pragma unroll
        for (int n = 0; n < 8; ++n) b1[n].u = *(const uint4*)(gBn + n * (16 * 8192));
        U4 af; CVT_A(af, a0lo, a0hi);
        #pragma unroll
        for (int n = 0; n < 8; ++n) acc[n] = mfma16(af.b, b0[n].b, acc[n]);
        a0lo = a1lo; a0hi = a1hi;
        #pragma unroll
        for (int n = 0; n < 8; ++n) b0[n] = b1[n];
    }
    // it = 31: no prefetch
    {
        U4 af; CVT_A(af, a0lo, a0hi);
        #pragma unroll
        for (int n = 0; n < 8; ++n) acc[n] = mfma16(af.b, b0[n].b, acc[n]);
    }
#undef CVT_A

    // epilogue: fp32 atomic accumulate (split-K)
    const int col = lane & 15;
    const int r0  = mbase + (wave << 4) + ((lane >> 4) << 2);
    #pragma unroll
    for (int n = 0; n < 8; ++n)
        #pragma unroll
        for (int r = 0; r < 4; ++r)
            atomicAdd(&C[(r0 + r) * 128 + (n << 4) + col], acc[n][r]);
}

// ---------------------------------------------------------------------------
// Kernel 2: h = relu(x@Ws0^T + neigh1@Wn0^T) -> bf16 [8192][256]
// Block tile 32m x 256n, 4 waves (2m x 2n). K = 128 + 128. No LDS.
// ---------------------------------------------------------------------------
__global__ __launch_bounds__(256) void h_kernel(
    const unsigned short* __restrict__ xb, const float* __restrict__ ng,
    const unsigned short* __restrict__ wcat, unsigned short* __restrict__ h)
{
    const int t = threadIdx.x, lane = t & 63, wave = t >> 6;
    const int wm = wave & 1, wn = wave >> 1;
    const int mbase = blockIdx.x * 32 + wm * 16;
    const int nbase = wn * 128;
    const int row = mbase + (lane & 15);
    const int ko  = (lane >> 4) << 3;

    f32x4 acc[8];
    #pragma unroll
    for (int n = 0; n < 8; ++n) acc[n] = (f32x4){0.f, 0.f, 0.f, 0.f};

    // self part: x (bf16) @ Ws0^T
    const unsigned short* xl = xb + row * 128 + ko;
    const unsigned short* w0 = wcat + (nbase + (lane & 15)) * 128 + ko;
    #pragma unroll
    for (int ks = 0; ks < 4; ++ks) {
        U4 a; a.u = *(const uint4*)(xl + ks * 32);
        #pragma unroll
        for (int n = 0; n < 8; ++n) {
            U4 b; b.u = *(const uint4*)(w0 + n * (16 * 128) + ks * 32);
            acc[n] = mfma16(a.b, b.b, acc[n]);
        }
    }
    // neighbor part: neigh1 (fp32 -> bf16) @ Wn0^T
    const float* nl = ng + row * 128 + ko;
    const unsigned short* w1 = wcat + 32768 + (nbase + (lane & 15)) * 128 + ko;
    #pragma unroll
    for (int ks = 0; ks < 4; ++ks) {
        float4 f0 = *(const float4*)(nl + ks * 32);
        float4 f1 = *(const float4*)(nl + ks * 32 + 4);
        U4 a;
        a.u.x = (unsigned)f2bf(f0.x) | ((unsigned)f2bf(f0.y) << 16);
        a.u.y = (unsigned)f2bf(f0.z) | ((unsigned)f2bf(f0.w) << 16);
        a.u.z = (unsigned)f2bf(f1.x) | ((unsigned)f2bf(f1.y) << 16);
        a.u.w = (unsigned)f2bf(f1.z) | ((unsigned)f2bf(f1.w) << 16);
        #pragma unroll
        for (int n = 0; n < 8; ++n) {
            U4 b; b.u = *(const uint4*)(w1 + n * (16 * 128) + ks * 32);
            acc[n] = mfma16(a.b, b.b, acc[n]);
        }
    }
    // relu + store bf16
    #pragma unroll
    for (int n = 0; n < 8; ++n)
        #pragma unroll
        for (int r = 0; r < 4; ++r) {
            int m = mbase + ((lane >> 4) << 2) + r;
            int c = nbase + (n << 4) + (lane & 15);
            float v = acc[n][r];
            h[m * 256 + c] = f2bf(v > 0.f ? v : 0.f);
        }
}

// ---------------------------------------------------------------------------
// Kernel 3: pT = (h @ Wn1^T)^T -> bf16 [128][8192]  (transposed for neigh_gemm)
// Block tile 32m x 128n, 4 waves (2m x 2n). K = 256.
// ---------------------------------------------------------------------------
__global__ __launch_bounds__(256) void p_kernel(
    const unsigned short* __restrict__ h, const unsigned short* __restrict__ wn1,
    unsigned short* __restrict__ pT)
{
    __shared__ unsigned short PT[128][40];       // [n][m] padded
    const int t = threadIdx.x, lane = t & 63, wave = t >> 6;
    const int wm = wave & 1, wn = wave >> 1;
    const int mbase = blockIdx.x * 32 + wm * 16;
    const int nbase = wn * 64;
    const int ko = (lane >> 4) << 3;

    f32x4 acc[4];
    #pragma unroll
    for (int n = 0; n < 4; ++n) acc[n] = (f32x4){0.f, 0.f, 0.f, 0.f};

    const unsigned short* hl = h + (mbase + (lane & 15)) * 256 + ko;
    const unsigned short* wl = wn1 + (nbase + (lane & 15)) * 256 + ko;
    #pragma unroll
    for (int ks = 0; ks < 8; ++ks) {
        U4 a; a.u = *(const uint4*)(hl + ks * 32);
        #pragma unroll
        for (int n = 0; n < 4; ++n) {
            U4 b; b.u = *(const uint4*)(wl + n * (16 * 256) + ks * 32);
            acc[n] = mfma16(a.b, b.b, acc[n]);
        }
    }
    // transpose through LDS: lane holds 4 consecutive m at fixed n
    const int m0 = wm * 16 + ((lane >> 4) << 2);
    #pragma unroll
    for (int n = 0; n < 4; ++n) {
        int c = nbase + (n << 4) + (lane & 15);
        unsigned int u0 = (unsigned)f2bf(acc[n][0]) | ((unsigned)f2bf(acc[n][1]) << 16);
        unsigned int u1 = (unsigned)f2bf(acc[n][2]) | ((unsigned)f2bf(acc[n][3]) << 16);
        *(uint2*)&PT[c][m0] = make_uint2(u0, u1);
    }
    __syncthreads();
    const int c = t >> 1, half = t & 1;
    const uint4* src = (const uint4*)&PT[c][half * 16];
    uint4* dst = (uint4*)(pT + c * 8192 + blockIdx.x * 32 + half * 16);
    dst[0] = src[0]; dst[1] = src[1];
}

// ---------------------------------------------------------------------------
// Kernel 4: out = relu(h@Ws1^T + t) fp32 [8192][128]
// ---------------------------------------------------------------------------
__global__ __launch_bounds__(256) void out_kernel(
    const unsigned short* __restrict__ h, const unsigned short* __restrict__ ws1,
    const float* __restrict__ tacc, float* __restrict__ out)
{
    const int t = threadIdx.x, lane = t & 63, wave = t >> 6;
    const int wm = wave & 1, wn = wave >> 1;
    const int mbase = blockIdx.x * 32 + wm * 16;
    const int nbase = wn * 64;
    const int ko = (lane >> 4) << 3;

    f32x4 acc[4];
    #pragma unroll
    for (int n = 0; n < 4; ++n) acc[n] = (f32x4){0.f, 0.f, 0.f, 0.f};

    const unsigned short* hl = h + (mbase + (lane & 15)) * 256 + ko;
    const unsigned short* wl = ws1 + (nbase + (lane & 15)) * 256 + ko;
    #pragma unroll
    for (int ks = 0; ks < 8; ++ks) {
        U4 a; a.u = *(const uint4*)(hl + ks * 32);
        #pragma unroll
        for (int n = 0; n < 4; ++n) {
            U4 b; b.u = *(const uint4*)(wl + n * (16 * 256) + ks * 32);
            acc[n] = mfma16(a.b, b.b, acc[n]);
        }
    }
    #pragma unroll
    for (int n = 0; n < 4; ++n)
        #pragma unroll
        for (int r = 0; r < 4; ++r) {
            int m = mbase + ((lane >> 4) << 2) + r;
            int c = nbase + (n << 4) + (lane & 15);
            int idx = m * 128 + c;
            float v = acc[n][r] + tacc[idx];
            out[idx] = v > 0.f ? v : 0.f;
        }
}

// ---------------------------------------------------------------------------
extern "C" void kernel_launch(void* const* d_in, const int* in_sizes, int n_in,
                              void* d_out, int out_size, void* d_ws, size_t ws_size,
                              hipStream_t stream)
{
    const float* x   = (const float*)d_in[0];
    const int*   adj = (const int*)d_in[1];
    const float* ws0 = (const float*)d_in[2];
    const float* wn0 = (const float*)d_in[3];
    const float* ws1 = (const float*)d_in[4];
    const float* wn1 = (const float*)d_in[5];
    float* out = (float*)d_out;

    char* ws = (char*)d_ws;
    float*          neigh1 = (float*)(ws);                        // 4 MB
    float*          tacc   = (float*)(ws + (4 << 20));            // 4 MB
    unsigned short* xb     = (unsigned short*)(ws + (8 << 20));   // 2 MB
    unsigned short* xT     = (unsigned short*)(ws + (10 << 20));  // 2 MB
    unsigned short* h      = (unsigned short*)(ws + (12 << 20));  // 4 MB
    unsigned short* pT     = (unsigned short*)(ws + (16 << 20));  // 2 MB
    unsigned short* wcat   = (unsigned short*)(ws + (18 << 20));  // 256 KB

    // zero the split-K accumulators
    hipMemsetAsync(ws, 0, 8 << 20, stream);

    convert_kernel<<<136, 256, 0, stream>>>(x, ws0, wn0, ws1, wn1, xb, xT, wcat);
    neigh_gemm<<<1024, 256, 0, stream>>>(adj, (const __hip_bfloat16*)xT, neigh1);
    h_kernel<<<256, 256, 0, stream>>>(xb, neigh1, wcat, h);
    p_kernel<<<256, 256, 0, stream>>>(h, wcat + 98304, pT);
    neigh_gemm<<<1024, 256, 0, stream>>>(adj, (const __hip_bfloat16*)pT, tacc);
    out_kernel<<<256, 256, 0, stream>>>(h, wcat + 65536, tacc, out);
}

// Round 3
// 272.862 us; speedup vs baseline: 1.3820x; 1.3820x over previous
//
#include <hip/hip_runtime.h>
#include <hip/hip_bf16.h>
#include <stdint.h>

// GNN 2-layer: out = relu(h@Ws1^T + A@(h@Wn1^T)), h = relu(x@Ws0^T + (A@x)@Wn0^T)
// A = [8192][8192] int32 {0,1}. Floor: streaming A twice (~133MB HBM each after L3).
// Key change this round: B operand pre-permuted into MFMA-fragment-linear layout
// Bf[(k>>5)*8 + n][lane] (16B units) so every B load is 1KB fully sequential.

typedef __attribute__((ext_vector_type(8))) short bf16x8;   // 8 bf16 in 4 VGPRs
typedef __attribute__((ext_vector_type(4))) float f32x4;

union U4 { uint4 u; int4 i; bf16x8 b; };

__device__ inline f32x4 mfma16(bf16x8 a, bf16x8 b, f32x4 c) {
    return __builtin_amdgcn_mfma_f32_16x16x32_bf16(a, b, c, 0, 0, 0);
}

__device__ inline unsigned short f2bf(float f) {
    union { float f; unsigned int u; } v; v.f = f;
    unsigned int u = v.u;
    return (unsigned short)((u + 0x7FFFu + ((u >> 16) & 1u)) >> 16);  // RNE
}

// ---------------------------------------------------------------------------
// Kernel 0: x -> x_bf16 [8192][128] and Bf1 (fragment-linear B layout for pass1);
//           4 weight matrices -> wcat bf16 (ws0|wn0|ws1|wn1).
// Bf unit (s,n,lane) holds x[s*32 + (lane>>4)*8 + j][n*16 + (lane&15)], j=0..7.
// ---------------------------------------------------------------------------
__global__ __launch_bounds__(256) void convert_kernel(
    const float* __restrict__ x,
    const float* __restrict__ w0, const float* __restrict__ w1,
    const float* __restrict__ w2, const float* __restrict__ w3,
    unsigned short* __restrict__ xb, unsigned short* __restrict__ Bf1,
    unsigned short* __restrict__ wcat)
{
    const int bid = blockIdx.x, t = threadIdx.x;
    if (bid < 128) {
        // 64 rows of x per block (k-steps 2*bid, 2*bid+1)
        __shared__ unsigned short XT[128][72];   // [col][local row], 144B rows
        const int base = bid * 8192;             // 64 rows * 128 cols
        #pragma unroll
        for (int i = 0; i < 32; ++i) {
            int off = i * 256 + t;
            unsigned short b = f2bf(x[base + off]);
            xb[base + off] = b;
            XT[off & 127][off >> 7] = b;         // [col][local row]
        }
        __syncthreads();
        // emit 1024 fragment units (16B each)
        uint4* dst = (uint4*)Bf1;
        #pragma unroll
        for (int i = 0; i < 4; ++i) {
            int u  = i * 256 + t;
            int sl = u >> 9;                     // local k-step 0/1
            int n  = (u >> 6) & 7;
            int ln = u & 63;
            int col = n * 16 + (ln & 15);
            const uint4* src = (const uint4*)&XT[col][sl * 32 + ((ln >> 4) << 3)];
            dst[((bid * 2 + sl) * 8 + n) * 64 + ln] = *src;
        }
    } else {
        // weights: 131072 elements over 8 blocks
        int w = (bid - 128) * 16384 + t;
        #pragma unroll
        for (int i = 0; i < 64; ++i, w += 256) {
            float v;
            if      (w < 32768)  v = w0[w];
            else if (w < 65536)  v = w1[w - 32768];
            else if (w < 98304)  v = w2[w - 65536];
            else                 v = w3[w - 98304];
            wcat[w] = f2bf(v);
        }
    }
}

// ---------------------------------------------------------------------------
// Kernel 1 (used twice): C[8192][128] += A_chunk @ B with B pre-permuted to
// fragment-linear layout Bf. Split-K = 8, grid 1024, 4 waves/block, each wave
// owns 16 rows. A: direct dwordx4 fragment loads (line-dense: 4 lanes = 64B
// per row), depth-3 reg pipeline. B: 1KB fully-sequential loads, depth 1.
// Full K-loop unroll -> static register rotation, no copies.
// ---------------------------------------------------------------------------
__global__ __launch_bounds__(256, 4) void neigh_gemm(
    const int* __restrict__ A, const unsigned short* __restrict__ Bf,
    float* __restrict__ C)
{
    const int t    = threadIdx.x;
    const int lane = t & 63;
    const int wave = t >> 6;
    const int bid  = blockIdx.x;
    const int mbase = (bid >> 3) << 6;           // 0..8128 step 64
    const int kbase = (bid & 7) << 10;           // k-chunk of 1024

    const int frow  = mbase + (wave << 4) + (lane & 15);
    const int kslot = (lane >> 4) << 3;          // 0,8,16,24

    const int*   gA  = A + frow * 8192 + kbase + kslot;
    const uint4* gBu = (const uint4*)Bf + (kbase >> 5) * 512 + lane;

    f32x4 acc[8];
    #pragma unroll
    for (int n = 0; n < 8; ++n) acc[n] = (f32x4){0.f, 0.f, 0.f, 0.f};

#define CVT_A(af, lo, hi)                                      \
    af.u.x = (unsigned)(lo.x | (lo.y << 16)) * 0x3F80u;        \
    af.u.y = (unsigned)(lo.z | (lo.w << 16)) * 0x3F80u;        \
    af.u.z = (unsigned)(hi.x | (hi.y << 16)) * 0x3F80u;        \
    af.u.w = (unsigned)(hi.z | (hi.w << 16)) * 0x3F80u;

    int4 aLo[3], aHi[3];
    U4 b0[8];
    #pragma unroll
    for (int p = 0; p < 3; ++p) {
        aLo[p] = *(const int4*)(gA + p * 32);
        aHi[p] = *(const int4*)(gA + p * 32 + 4);
    }
    #pragma unroll
    for (int n = 0; n < 8; ++n) b0[n].u = gBu[n * 64];

    #pragma unroll
    for (int it = 0; it < 32; ++it) {
        U4 b1[8];
        if (it < 31) {
            #pragma unroll
            for (int n = 0; n < 8; ++n) b1[n].u = gBu[(it + 1) * 512 + n * 64];
        }
        int4 nLo, nHi;
        if (it < 29) {
            nLo = *(const int4*)(gA + (it + 3) * 32);
            nHi = *(const int4*)(gA + (it + 3) * 32 + 4);
        }
        U4 af; CVT_A(af, aLo[it % 3], aHi[it % 3]);
        #pragma unroll
        for (int n = 0; n < 8; ++n) acc[n] = mfma16(af.b, b0[n].b, acc[n]);
        if (it < 29) { aLo[it % 3] = nLo; aHi[it % 3] = nHi; }
        if (it < 31) {
            #pragma unroll
            for (int n = 0; n < 8; ++n) b0[n] = b1[n];
        }
    }
#undef CVT_A

    // epilogue: fp32 atomic accumulate (split-K)
    const int col = lane & 15;
    const int r0  = mbase + (wave << 4) + ((lane >> 4) << 2);
    #pragma unroll
    for (int n = 0; n < 8; ++n)
        #pragma unroll
        for (int r = 0; r < 4; ++r)
            atomicAdd(&C[(r0 + r) * 128 + (n << 4) + col], acc[n][r]);
}

// ---------------------------------------------------------------------------
// Kernel 2: h = relu(x@Ws0^T + neigh1@Wn0^T) -> bf16 [8192][256]
// Block tile 32m x 256n, 4 waves (2m x 2n). K = 128 + 128. No LDS.
// ---------------------------------------------------------------------------
__global__ __launch_bounds__(256) void h_kernel(
    const unsigned short* __restrict__ xb, const float* __restrict__ ng,
    const unsigned short* __restrict__ wcat, unsigned short* __restrict__ h)
{
    const int t = threadIdx.x, lane = t & 63, wave = t >> 6;
    const int wm = wave & 1, wn = wave >> 1;
    const int mbase = blockIdx.x * 32 + wm * 16;
    const int nbase = wn * 128;
    const int row = mbase + (lane & 15);
    const int ko  = (lane >> 4) << 3;

    f32x4 acc[8];
    #pragma unroll
    for (int n = 0; n < 8; ++n) acc[n] = (f32x4){0.f, 0.f, 0.f, 0.f};

    // self part: x (bf16) @ Ws0^T
    const unsigned short* xl = xb + row * 128 + ko;
    const unsigned short* w0 = wcat + (nbase + (lane & 15)) * 128 + ko;
    #pragma unroll
    for (int ks = 0; ks < 4; ++ks) {
        U4 a; a.u = *(const uint4*)(xl + ks * 32);
        #pragma unroll
        for (int n = 0; n < 8; ++n) {
            U4 b; b.u = *(const uint4*)(w0 + n * (16 * 128) + ks * 32);
            acc[n] = mfma16(a.b, b.b, acc[n]);
        }
    }
    // neighbor part: neigh1 (fp32 -> bf16) @ Wn0^T
    const float* nl = ng + row * 128 + ko;
    const unsigned short* w1 = wcat + 32768 + (nbase + (lane & 15)) * 128 + ko;
    #pragma unroll
    for (int ks = 0; ks < 4; ++ks) {
        float4 f0 = *(const float4*)(nl + ks * 32);
        float4 f1 = *(const float4*)(nl + ks * 32 + 4);
        U4 a;
        a.u.x = (unsigned)f2bf(f0.x) | ((unsigned)f2bf(f0.y) << 16);
        a.u.y = (unsigned)f2bf(f0.z) | ((unsigned)f2bf(f0.w) << 16);
        a.u.z = (unsigned)f2bf(f1.x) | ((unsigned)f2bf(f1.y) << 16);
        a.u.w = (unsigned)f2bf(f1.z) | ((unsigned)f2bf(f1.w) << 16);
        #pragma unroll
        for (int n = 0; n < 8; ++n) {
            U4 b; b.u = *(const uint4*)(w1 + n * (16 * 128) + ks * 32);
            acc[n] = mfma16(a.b, b.b, acc[n]);
        }
    }
    // relu + store bf16
    #pragma unroll
    for (int n = 0; n < 8; ++n)
        #pragma unroll
        for (int r = 0; r < 4; ++r) {
            int m = mbase + ((lane >> 4) << 2) + r;
            int c = nbase + (n << 4) + (lane & 15);
            float v = acc[n][r];
            h[m * 256 + c] = f2bf(v > 0.f ? v : 0.f);
        }
}

// ---------------------------------------------------------------------------
// Kernel 3: p = h @ Wn1^T, emitted directly in fragment-linear layout Bf2.
// Block tile 32m x 128n (= one k-step of pass 2), 4 waves (2m x 2n). K = 256.
// ---------------------------------------------------------------------------
__global__ __launch_bounds__(256) void p_kernel(
    const unsigned short* __restrict__ h, const unsigned short* __restrict__ wn1,
    unsigned short* __restrict__ Bf2)
{
    __shared__ unsigned short PT[128][48];       // [col][m], 96B rows (16B-mult)
    const int t = threadIdx.x, lane = t & 63, wave = t >> 6;
    const int wm = wave & 1, wn = wave >> 1;
    const int mbase = blockIdx.x * 32 + wm * 16;
    const int nbase = wn * 64;
    const int ko = (lane >> 4) << 3;

    f32x4 acc[4];
    #pragma unroll
    for (int n = 0; n < 4; ++n) acc[n] = (f32x4){0.f, 0.f, 0.f, 0.f};

    const unsigned short* hl = h + (mbase + (lane & 15)) * 256 + ko;
    const unsigned short* wl = wn1 + (nbase + (lane & 15)) * 256 + ko;
    #pragma unroll
    for (int ks = 0; ks < 8; ++ks) {
        U4 a; a.u = *(const uint4*)(hl + ks * 32);
        #pragma unroll
        for (int n = 0; n < 4; ++n) {
            U4 b; b.u = *(const uint4*)(wl + n * (16 * 256) + ks * 32);
            acc[n] = mfma16(a.b, b.b, acc[n]);
        }
    }
    // scatter to LDS: lane holds 4 consecutive m at fixed col
    const int m0 = wm * 16 + ((lane >> 4) << 2);
    #pragma unroll
    for (int n = 0; n < 4; ++n) {
        int c = nbase + (n << 4) + (lane & 15);
        unsigned int u0 = (unsigned)f2bf(acc[n][0]) | ((unsigned)f2bf(acc[n][1]) << 16);
        unsigned int u1 = (unsigned)f2bf(acc[n][2]) | ((unsigned)f2bf(acc[n][3]) << 16);
        *(uint2*)&PT[c][m0] = make_uint2(u0, u1);
    }
    __syncthreads();
    // emit 512 fragment units: Bf2[(bid*8+n)*64 + lane] = PT[16n+(ln&15)][(ln>>4)*8 ..]
    uint4* dst = (uint4*)Bf2;
    #pragma unroll
    for (int i = 0; i < 2; ++i) {
        int u  = i * 256 + t;
        int n  = u >> 6;
        int ln = u & 63;
        const uint4* src = (const uint4*)&PT[n * 16 + (ln & 15)][(ln >> 4) << 3];
        dst[(blockIdx.x * 8 + n) * 64 + ln] = *src;
    }
}

// ---------------------------------------------------------------------------
// Kernel 4: out = relu(h@Ws1^T + t) fp32 [8192][128]
// ---------------------------------------------------------------------------
__global__ __launch_bounds__(256) void out_kernel(
    const unsigned short* __restrict__ h, const unsigned short* __restrict__ ws1,
    const float* __restrict__ tacc, float* __restrict__ out)
{
    const int t = threadIdx.x, lane = t & 63, wave = t >> 6;
    const int wm = wave & 1, wn = wave >> 1;
    const int mbase = blockIdx.x * 32 + wm * 16;
    const int nbase = wn * 64;
    const int ko = (lane >> 4) << 3;

    f32x4 acc[4];
    #pragma unroll
    for (int n = 0; n < 4; ++n) acc[n] = (f32x4){0.f, 0.f, 0.f, 0.f};

    const unsigned short* hl = h + (mbase + (lane & 15)) * 256 + ko;
    const unsigned short* wl = ws1 + (nbase + (lane & 15)) * 256 + ko;
    #pragma unroll
    for (int ks = 0; ks < 8; ++ks) {
        U4 a; a.u = *(const uint4*)(hl + ks * 32);
        #pragma unroll
        for (int n = 0; n < 4; ++n) {
            U4 b; b.u = *(const uint4*)(wl + n * (16 * 256) + ks * 32);
            acc[n] = mfma16(a.b, b.b, acc[n]);
        }
    }
    #pragma unroll
    for (int n = 0; n < 4; ++n)
        #pragma unroll
        for (int r = 0; r < 4; ++r) {
            int m = mbase + ((lane >> 4) << 2) + r;
            int c = nbase + (n << 4) + (lane & 15);
            int idx = m * 128 + c;
            float v = acc[n][r] + tacc[idx];
            out[idx] = v > 0.f ? v : 0.f;
        }
}

// ---------------------------------------------------------------------------
extern "C" void kernel_launch(void* const* d_in, const int* in_sizes, int n_in,
                              void* d_out, int out_size, void* d_ws, size_t ws_size,
                              hipStream_t stream)
{
    const float* x   = (const float*)d_in[0];
    const int*   adj = (const int*)d_in[1];
    const float* ws0 = (const float*)d_in[2];
    const float* wn0 = (const float*)d_in[3];
    const float* ws1 = (const float*)d_in[4];
    const float* wn1 = (const float*)d_in[5];
    float* out = (float*)d_out;

    char* ws = (char*)d_ws;
    float*          neigh1 = (float*)(ws);                        // 4 MB
    float*          tacc   = (float*)(ws + (4 << 20));            // 4 MB
    unsigned short* xb     = (unsigned short*)(ws + (8 << 20));   // 2 MB
    unsigned short* Bf1    = (unsigned short*)(ws + (10 << 20));  // 2 MB
    unsigned short* h      = (unsigned short*)(ws + (12 << 20));  // 4 MB
    unsigned short* Bf2    = (unsigned short*)(ws + (16 << 20));  // 2 MB
    unsigned short* wcat   = (unsigned short*)(ws + (18 << 20));  // 256 KB

    // zero the split-K accumulators
    hipMemsetAsync(ws, 0, 8 << 20, stream);

    convert_kernel<<<136, 256, 0, stream>>>(x, ws0, wn0, ws1, wn1, xb, Bf1, wcat);
    neigh_gemm<<<1024, 256, 0, stream>>>(adj, Bf1, neigh1);
    h_kernel<<<256, 256, 0, stream>>>(xb, neigh1, wcat, h);
    p_kernel<<<256, 256, 0, stream>>>(h, wcat + 98304, Bf2);
    neigh_gemm<<<1024, 256, 0, stream>>>(adj, Bf2, tacc);
    out_kernel<<<256, 256, 0, stream>>>(h, wcat + 65536, tacc, out);
}

// Round 4
// 248.388 us; speedup vs baseline: 1.5181x; 1.0985x over previous
//
#include <hip/hip_runtime.h>
#include <hip/hip_bf16.h>
#include <stdint.h>

// GNN 2-layer: out = relu(h@Ws1^T + A@(h@Wn1^T)), h = relu(x@Ws0^T + (A@x)@Wn0^T)
// A = [8192][8192] int32 {0,1}.
// R4 theory: R1-R3's invariant ~160-190us neigh_gemm was DRAM row-buffer thrash
// from 128B-granule reads at 32KB stride (16 rows/wave). Fix: pack_A pre-pass
// streams A sequentially (4KB runs/row) into bf16 FRAGMENT-LINEAR Af (128MB);
// neigh passes then read Af as contiguous 32KB/wave streams. Pass2 hits L3.

typedef __attribute__((ext_vector_type(8))) short bf16x8;   // 8 bf16 in 4 VGPRs
typedef __attribute__((ext_vector_type(4))) float f32x4;

union U4 { uint4 u; int4 i; bf16x8 b; };

__device__ inline f32x4 mfma16(bf16x8 a, bf16x8 b, f32x4 c) {
    return __builtin_amdgcn_mfma_f32_16x16x32_bf16(a, b, c, 0, 0, 0);
}

__device__ inline unsigned short f2bf(float f) {
    union { float f; unsigned int u; } v; v.f = f;
    unsigned int u = v.u;
    return (unsigned short)((u + 0x7FFFu + ((u >> 16) & 1u)) >> 16);  // RNE
}

// ---------------------------------------------------------------------------
// pack_A: A int32 [8192][8192] -> Af bf16 fragment-linear.
// Block = (mt = 16-row group 0..511, kc = 1024-k chunk 0..7).
// Unit (mt,kc,s,lane) 16B holds A[mt*16 + (lane&15)][kc*1024 + s*32 + (lane>>4)*8 + j].
// Reads: 16 rows x 4KB sequential runs. Writes: 32KB contiguous per block.
// ---------------------------------------------------------------------------
__global__ __launch_bounds__(256) void pack_A(
    const int* __restrict__ A, unsigned short* __restrict__ Af)
{
    __shared__ unsigned short L[16][1032];        // row stride 2064B (bank-friendly)
    const int bid = blockIdx.x, t = threadIdx.x, lane = t & 63, w = t >> 6;
    const int mt = bid >> 3, kc = bid & 7;
    const long base = (long)mt * 16 * 8192 + kc * 1024;

    // phase 1: wave w converts rows [4w, 4w+4), each row 4x1KB sequential
    #pragma unroll
    for (int rr = 0; rr < 4; ++rr) {
        const int r = w * 4 + rr;
        const int4* src = (const int4*)(A + base + (long)r * 8192) + lane;
        #pragma unroll
        for (int i = 0; i < 4; ++i) {
            int4 v = src[i * 64];
            unsigned lo = (unsigned)(v.x | (v.y << 16)) * 0x3F80u;
            unsigned hi = (unsigned)(v.z | (v.w << 16)) * 0x3F80u;
            *(uint2*)&L[r][(i * 64 + lane) * 4] = make_uint2(lo, hi);
        }
    }
    __syncthreads();
    // phase 2: emit 2048 units of 16B, fully sequential global writes
    uint4* dst = (uint4*)Af + (size_t)bid * 2048;
    #pragma unroll
    for (int i = 0; i < 8; ++i) {
        int g = i * 256 + t, s = g >> 6, l = g & 63;
        dst[g] = *(const uint4*)&L[l & 15][s * 32 + ((l >> 4) << 3)];
    }
}

// ---------------------------------------------------------------------------
// Kernel 0: x -> x_bf16 [8192][128] and Bf1 (fragment-linear B for pass1);
//           4 weight matrices -> wcat bf16 (ws0|wn0|ws1|wn1).
// ---------------------------------------------------------------------------
__global__ __launch_bounds__(256) void convert_kernel(
    const float* __restrict__ x,
    const float* __restrict__ w0, const float* __restrict__ w1,
    const float* __restrict__ w2, const float* __restrict__ w3,
    unsigned short* __restrict__ xb, unsigned short* __restrict__ Bf1,
    unsigned short* __restrict__ wcat)
{
    const int bid = blockIdx.x, t = threadIdx.x;
    if (bid < 128) {
        __shared__ unsigned short XT[128][72];   // [col][local row]
        const int base = bid * 8192;             // 64 rows * 128 cols
        #pragma unroll
        for (int i = 0; i < 32; ++i) {
            int off = i * 256 + t;
            unsigned short b = f2bf(x[base + off]);
            xb[base + off] = b;
            XT[off & 127][off >> 7] = b;
        }
        __syncthreads();
        uint4* dst = (uint4*)Bf1;
        #pragma unroll
        for (int i = 0; i < 4; ++i) {
            int u  = i * 256 + t;
            int sl = u >> 9;                     // local k-step 0/1
            int n  = (u >> 6) & 7;
            int ln = u & 63;
            int col = n * 16 + (ln & 15);
            const uint4* src = (const uint4*)&XT[col][sl * 32 + ((ln >> 4) << 3)];
            dst[((bid * 2 + sl) * 8 + n) * 64 + ln] = *src;
        }
    } else {
        int w = (bid - 128) * 16384 + t;
        #pragma unroll
        for (int i = 0; i < 64; ++i, w += 256) {
            float v;
            if      (w < 32768)  v = w0[w];
            else if (w < 65536)  v = w1[w - 32768];
            else if (w < 98304)  v = w2[w - 65536];
            else                 v = w3[w - 98304];
            wcat[w] = f2bf(v);
        }
    }
}

// ---------------------------------------------------------------------------
// neigh_gemm (x2): C[8192][128] += A_chunk @ B, both operands fragment-linear.
// Split-K=8, grid 1024, 4 waves/block, wave owns 16 rows (mt = m64*4 + w).
// A: 1 contiguous-1KB load/step (depth-3 reg pipeline, 32KB/wave stream).
// B: 8 contiguous loads/step = 8KB (depth-2, L2-hot 256KB/k-chunk).
// ---------------------------------------------------------------------------
__global__ __launch_bounds__(256, 3) void neigh_gemm(
    const unsigned short* __restrict__ Af, const unsigned short* __restrict__ Bf,
    float* __restrict__ C)
{
    const int t = threadIdx.x, lane = t & 63, w = t >> 6, bid = blockIdx.x;
    const int m64 = bid >> 3, kc = bid & 7;
    const int mt  = m64 * 4 + w;

    const uint4* gA = (const uint4*)Af + (size_t)(mt * 8 + kc) * 2048 + lane;
    const uint4* gB = (const uint4*)Bf + (size_t)kc * 16384 + lane;

    f32x4 acc[8];
    #pragma unroll
    for (int n = 0; n < 8; ++n) acc[n] = (f32x4){0.f, 0.f, 0.f, 0.f};

    U4 a[3];
    U4 b[2][8];
    #pragma unroll
    for (int p = 0; p < 3; ++p) a[p].u = gA[p * 64];
    #pragma unroll
    for (int d = 0; d < 2; ++d)
        #pragma unroll
        for (int n = 0; n < 8; ++n) b[d][n].u = gB[d * 512 + n * 64];

    #pragma unroll
    for (int it = 0; it < 32; ++it) {
        U4 af = a[it % 3];
        if (it < 29) a[it % 3].u = gA[(it + 3) * 64];     // A prefetch depth 3
        #pragma unroll
        for (int n = 0; n < 8; ++n)
            acc[n] = mfma16(af.b, b[it & 1][n].b, acc[n]);
        if (it < 30) {                                     // B prefetch depth 2
            #pragma unroll
            for (int n = 0; n < 8; ++n) b[it & 1][n].u = gB[(it + 2) * 512 + n * 64];
        }
    }

    // epilogue: fp32 atomic accumulate (split-K)
    const int col = lane & 15;
    const int r0  = mt * 16 + ((lane >> 4) << 2);
    #pragma unroll
    for (int n = 0; n < 8; ++n)
        #pragma unroll
        for (int r = 0; r < 4; ++r)
            atomicAdd(&C[(r0 + r) * 128 + (n << 4) + col], acc[n][r]);
}

// ---------------------------------------------------------------------------
// Fallback neigh_gemm reading A directly as int32 (if ws too small for Af).
// ---------------------------------------------------------------------------
__global__ __launch_bounds__(256, 4) void neigh_gemm_direct(
    const int* __restrict__ A, const unsigned short* __restrict__ Bf,
    float* __restrict__ C)
{
    const int t = threadIdx.x, lane = t & 63, wave = t >> 6, bid = blockIdx.x;
    const int mbase = (bid >> 3) << 6;
    const int kbase = (bid & 7) << 10;
    const int frow  = mbase + (wave << 4) + (lane & 15);
    const int kslot = (lane >> 4) << 3;

    const int*   gA  = A + frow * 8192 + kbase + kslot;
    const uint4* gBu = (const uint4*)Bf + (kbase >> 5) * 512 + lane;

    f32x4 acc[8];
    #pragma unroll
    for (int n = 0; n < 8; ++n) acc[n] = (f32x4){0.f, 0.f, 0.f, 0.f};

#define CVT_A(af, lo, hi)                                      \
    af.u.x = (unsigned)(lo.x | (lo.y << 16)) * 0x3F80u;        \
    af.u.y = (unsigned)(lo.z | (lo.w << 16)) * 0x3F80u;        \
    af.u.z = (unsigned)(hi.x | (hi.y << 16)) * 0x3F80u;        \
    af.u.w = (unsigned)(hi.z | (hi.w << 16)) * 0x3F80u;

    int4 aLo[3], aHi[3];
    U4 b0[8];
    #pragma unroll
    for (int p = 0; p < 3; ++p) {
        aLo[p] = *(const int4*)(gA + p * 32);
        aHi[p] = *(const int4*)(gA + p * 32 + 4);
    }
    #pragma unroll
    for (int n = 0; n < 8; ++n) b0[n].u = gBu[n * 64];

    #pragma unroll
    for (int it = 0; it < 32; ++it) {
        U4 af; CVT_A(af, aLo[it % 3], aHi[it % 3]);
        if (it < 29) {
            aLo[it % 3] = *(const int4*)(gA + (it + 3) * 32);
            aHi[it % 3] = *(const int4*)(gA + (it + 3) * 32 + 4);
        }
        #pragma unroll
        for (int n = 0; n < 8; ++n) acc[n] = mfma16(af.b, b0[n].b, acc[n]);
        if (it < 31) {
            #pragma unroll
            for (int n = 0; n < 8; ++n) b0[n].u = gBu[(it + 1) * 512 + n * 64];
        }
    }
#undef CVT_A

    const int col = lane & 15;
    const int r0  = mbase + (wave << 4) + ((lane >> 4) << 2);
    #pragma unroll
    for (int n = 0; n < 8; ++n)
        #pragma unroll
        for (int r = 0; r < 4; ++r)
            atomicAdd(&C[(r0 + r) * 128 + (n << 4) + col], acc[n][r]);
}

// ---------------------------------------------------------------------------
// h_kernel: h = relu(x@Ws0^T + neigh1@Wn0^T) -> bf16 [8192][256]
// ---------------------------------------------------------------------------
__global__ __launch_bounds__(256) void h_kernel(
    const unsigned short* __restrict__ xb, const float* __restrict__ ng,
    const unsigned short* __restrict__ wcat, unsigned short* __restrict__ h)
{
    const int t = threadIdx.x, lane = t & 63, wave = t >> 6;
    const int wm = wave & 1, wn = wave >> 1;
    const int mbase = blockIdx.x * 32 + wm * 16;
    const int nbase = wn * 128;
    const int row = mbase + (lane & 15);
    const int ko  = (lane >> 4) << 3;

    f32x4 acc[8];
    #pragma unroll
    for (int n = 0; n < 8; ++n) acc[n] = (f32x4){0.f, 0.f, 0.f, 0.f};

    const unsigned short* xl = xb + row * 128 + ko;
    const unsigned short* w0 = wcat + (nbase + (lane & 15)) * 128 + ko;
    #pragma unroll
    for (int ks = 0; ks < 4; ++ks) {
        U4 a; a.u = *(const uint4*)(xl + ks * 32);
        #pragma unroll
        for (int n = 0; n < 8; ++n) {
            U4 b; b.u = *(const uint4*)(w0 + n * (16 * 128) + ks * 32);
            acc[n] = mfma16(a.b, b.b, acc[n]);
        }
    }
    const float* nl = ng + row * 128 + ko;
    const unsigned short* w1 = wcat + 32768 + (nbase + (lane & 15)) * 128 + ko;
    #pragma unroll
    for (int ks = 0; ks < 4; ++ks) {
        float4 f0 = *(const float4*)(nl + ks * 32);
        float4 f1 = *(const float4*)(nl + ks * 32 + 4);
        U4 a;
        a.u.x = (unsigned)f2bf(f0.x) | ((unsigned)f2bf(f0.y) << 16);
        a.u.y = (unsigned)f2bf(f0.z) | ((unsigned)f2bf(f0.w) << 16);
        a.u.z = (unsigned)f2bf(f1.x) | ((unsigned)f2bf(f1.y) << 16);
        a.u.w = (unsigned)f2bf(f1.z) | ((unsigned)f2bf(f1.w) << 16);
        #pragma unroll
        for (int n = 0; n < 8; ++n) {
            U4 b; b.u = *(const uint4*)(w1 + n * (16 * 128) + ks * 32);
            acc[n] = mfma16(a.b, b.b, acc[n]);
        }
    }
    #pragma unroll
    for (int n = 0; n < 8; ++n)
        #pragma unroll
        for (int r = 0; r < 4; ++r) {
            int m = mbase + ((lane >> 4) << 2) + r;
            int c = nbase + (n << 4) + (lane & 15);
            float v = acc[n][r];
            h[m * 256 + c] = f2bf(v > 0.f ? v : 0.f);
        }
}

// ---------------------------------------------------------------------------
// p_kernel: p = h @ Wn1^T, emitted in fragment-linear layout Bf2.
// ---------------------------------------------------------------------------
__global__ __launch_bounds__(256) void p_kernel(
    const unsigned short* __restrict__ h, const unsigned short* __restrict__ wn1,
    unsigned short* __restrict__ Bf2)
{
    __shared__ unsigned short PT[128][48];
    const int t = threadIdx.x, lane = t & 63, wave = t >> 6;
    const int wm = wave & 1, wn = wave >> 1;
    const int mbase = blockIdx.x * 32 + wm * 16;
    const int nbase = wn * 64;
    const int ko = (lane >> 4) << 3;

    f32x4 acc[4];
    #pragma unroll
    for (int n = 0; n < 4; ++n) acc[n] = (f32x4){0.f, 0.f, 0.f, 0.f};

    const unsigned short* hl = h + (mbase + (lane & 15)) * 256 + ko;
    const unsigned short* wl = wn1 + (nbase + (lane & 15)) * 256 + ko;
    #pragma unroll
    for (int ks = 0; ks < 8; ++ks) {
        U4 a; a.u = *(const uint4*)(hl + ks * 32);
        #pragma unroll
        for (int n = 0; n < 4; ++n) {
            U4 b; b.u = *(const uint4*)(wl + n * (16 * 256) + ks * 32);
            acc[n] = mfma16(a.b, b.b, acc[n]);
        }
    }
    const int m0 = wm * 16 + ((lane >> 4) << 2);
    #pragma unroll
    for (int n = 0; n < 4; ++n) {
        int c = nbase + (n << 4) + (lane & 15);
        unsigned int u0 = (unsigned)f2bf(acc[n][0]) | ((unsigned)f2bf(acc[n][1]) << 16);
        unsigned int u1 = (unsigned)f2bf(acc[n][2]) | ((unsigned)f2bf(acc[n][3]) << 16);
        *(uint2*)&PT[c][m0] = make_uint2(u0, u1);
    }
    __syncthreads();
    uint4* dst = (uint4*)Bf2;
    #pragma unroll
    for (int i = 0; i < 2; ++i) {
        int u  = i * 256 + t;
        int n  = u >> 6;
        int ln = u & 63;
        const uint4* src = (const uint4*)&PT[n * 16 + (ln & 15)][(ln >> 4) << 3];
        dst[(blockIdx.x * 8 + n) * 64 + ln] = *src;
    }
}

// ---------------------------------------------------------------------------
// out_kernel: out = relu(h@Ws1^T + tacc) fp32 [8192][128]
// ---------------------------------------------------------------------------
__global__ __launch_bounds__(256) void out_kernel(
    const unsigned short* __restrict__ h, const unsigned short* __restrict__ ws1,
    const float* __restrict__ tacc, float* __restrict__ out)
{
    const int t = threadIdx.x, lane = t & 63, wave = t >> 6;
    const int wm = wave & 1, wn = wave >> 1;
    const int mbase = blockIdx.x * 32 + wm * 16;
    const int nbase = wn * 64;
    const int ko = (lane >> 4) << 3;

    f32x4 acc[4];
    #pragma unroll
    for (int n = 0; n < 4; ++n) acc[n] = (f32x4){0.f, 0.f, 0.f, 0.f};

    const unsigned short* hl = h + (mbase + (lane & 15)) * 256 + ko;
    const unsigned short* wl = ws1 + (nbase + (lane & 15)) * 256 + ko;
    #pragma unroll
    for (int ks = 0; ks < 8; ++ks) {
        U4 a; a.u = *(const uint4*)(hl + ks * 32);
        #pragma unroll
        for (int n = 0; n < 4; ++n) {
            U4 b; b.u = *(const uint4*)(wl + n * (16 * 256) + ks * 32);
            acc[n] = mfma16(a.b, b.b, acc[n]);
        }
    }
    #pragma unroll
    for (int n = 0; n < 4; ++n)
        #pragma unroll
        for (int r = 0; r < 4; ++r) {
            int m = mbase + ((lane >> 4) << 2) + r;
            int c = nbase + (n << 4) + (lane & 15);
            int idx = m * 128 + c;
            float v = acc[n][r] + tacc[idx];
            out[idx] = v > 0.f ? v : 0.f;
        }
}

// ---------------------------------------------------------------------------
extern "C" void kernel_launch(void* const* d_in, const int* in_sizes, int n_in,
                              void* d_out, int out_size, void* d_ws, size_t ws_size,
                              hipStream_t stream)
{
    const float* x   = (const float*)d_in[0];
    const int*   adj = (const int*)d_in[1];
    const float* ws0 = (const float*)d_in[2];
    const float* wn0 = (const float*)d_in[3];
    const float* ws1 = (const float*)d_in[4];
    const float* wn1 = (const float*)d_in[5];
    float* out = (float*)d_out;

    char* ws = (char*)d_ws;
    float*          neigh1 = (float*)(ws);                        // 4 MB
    float*          tacc   = (float*)(ws + (4 << 20));            // 4 MB
    unsigned short* xb     = (unsigned short*)(ws + (8 << 20));   // 2 MB
    unsigned short* Bf1    = (unsigned short*)(ws + (10 << 20));  // 2 MB
    unsigned short* h      = (unsigned short*)(ws + (12 << 20));  // 4 MB
    unsigned short* Bf2    = (unsigned short*)(ws + (16 << 20));  // 2 MB
    unsigned short* wcat   = (unsigned short*)(ws + (18 << 20));  // 256 KB
    unsigned short* Af     = (unsigned short*)(ws + (19 << 20));  // 128 MB

    const bool packed = ws_size >= ((size_t)147 << 20);

    hipMemsetAsync(ws, 0, 8 << 20, stream);  // zero split-K accumulators

    if (packed) pack_A<<<4096, 256, 0, stream>>>(adj, Af);
    convert_kernel<<<136, 256, 0, stream>>>(x, ws0, wn0, ws1, wn1, xb, Bf1, wcat);
    if (packed) neigh_gemm<<<1024, 256, 0, stream>>>(Af, Bf1, neigh1);
    else        neigh_gemm_direct<<<1024, 256, 0, stream>>>(adj, Bf1, neigh1);
    h_kernel<<<256, 256, 0, stream>>>(xb, neigh1, wcat, h);
    p_kernel<<<256, 256, 0, stream>>>(h, wcat + 98304, Bf2);
    if (packed) neigh_gemm<<<1024, 256, 0, stream>>>(Af, Bf2, tacc);
    else        neigh_gemm_direct<<<1024, 256, 0, stream>>>(adj, Bf2, tacc);
    out_kernel<<<256, 256, 0, stream>>>(h, wcat + 65536, tacc, out);
}

// Round 5
// 245.305 us; speedup vs baseline: 1.5372x; 1.0126x over previous
//
#include <hip/hip_runtime.h>
#include <hip/hip_bf16.h>
#include <stdint.h>

// GNN 2-layer: out = relu(h@Ws1^T + A@(h@Wn1^T)), h = relu(x@Ws0^T + (A@x)@Wn0^T)
// A = [8192][8192] int32 {0,1}.
// R4 established: pack_A (sequential streams -> bf16 fragment-linear Af) fixed
// the DRAM row-buffer thrash; neigh_gemm dropped 157us -> ~15us.
// R5: the hidden top cost was our own 8MB hipMemsetAsync (rocclr fillBuffer =
// 154us @ 54GB/s, bad launch config). Replace with 512 extra pack_A blocks
// that zero the split-K accumulators with a proper grid.

typedef __attribute__((ext_vector_type(8))) short bf16x8;   // 8 bf16 in 4 VGPRs
typedef __attribute__((ext_vector_type(4))) float f32x4;

union U4 { uint4 u; int4 i; bf16x8 b; };

__device__ inline f32x4 mfma16(bf16x8 a, bf16x8 b, f32x4 c) {
    return __builtin_amdgcn_mfma_f32_16x16x32_bf16(a, b, c, 0, 0, 0);
}

__device__ inline unsigned short f2bf(float f) {
    union { float f; unsigned int u; } v; v.f = f;
    unsigned int u = v.u;
    return (unsigned short)((u + 0x7FFFu + ((u >> 16) & 1u)) >> 16);  // RNE
}

// ---------------------------------------------------------------------------
// pack_A: A int32 [8192][8192] -> Af bf16 fragment-linear.
// Blocks [0,4096): (mt = 16-row group, kc = 1024-k chunk).
// Unit (mt,kc,s,lane) 16B holds A[mt*16 + (lane&15)][kc*1024 + s*32 + (lane>>4)*8 + j].
// Reads: 16 rows x 4KB sequential runs. Writes: 32KB contiguous per block.
// Blocks [4096,4608): zero the 8MB split-K accumulator region (zbuf).
// ---------------------------------------------------------------------------
__global__ __launch_bounds__(256) void pack_A(
    const int* __restrict__ A, unsigned short* __restrict__ Af,
    uint4* __restrict__ zbuf)
{
    const int bid = blockIdx.x, t = threadIdx.x, lane = t & 63, w = t >> 6;
    if (bid >= 4096) {
        // zero 8MB: 512 blocks x 256 threads x 4 uint4 = 16KB/block
        uint4 z = make_uint4(0, 0, 0, 0);
        uint4* p = zbuf + (size_t)(bid - 4096) * 1024 + t;
        p[0] = z; p[256] = z; p[512] = z; p[768] = z;
        return;
    }
    __shared__ unsigned short L[16][1032];        // row stride 2064B (bank-friendly)
    const int mt = bid >> 3, kc = bid & 7;
    const long base = (long)mt * 16 * 8192 + kc * 1024;

    // phase 1: wave w converts rows [4w, 4w+4), each row 4x1KB sequential
    #pragma unroll
    for (int rr = 0; rr < 4; ++rr) {
        const int r = w * 4 + rr;
        const int4* src = (const int4*)(A + base + (long)r * 8192) + lane;
        #pragma unroll
        for (int i = 0; i < 4; ++i) {
            int4 v = src[i * 64];
            unsigned lo = (unsigned)(v.x | (v.y << 16)) * 0x3F80u;
            unsigned hi = (unsigned)(v.z | (v.w << 16)) * 0x3F80u;
            *(uint2*)&L[r][(i * 64 + lane) * 4] = make_uint2(lo, hi);
        }
    }
    __syncthreads();
    // phase 2: emit 2048 units of 16B, fully sequential global writes
    uint4* dst = (uint4*)Af + (size_t)bid * 2048;
    #pragma unroll
    for (int i = 0; i < 8; ++i) {
        int g = i * 256 + t, s = g >> 6, l = g & 63;
        dst[g] = *(const uint4*)&L[l & 15][s * 32 + ((l >> 4) << 3)];
    }
}

// ---------------------------------------------------------------------------
// Kernel 0: x -> x_bf16 [8192][128] and Bf1 (fragment-linear B for pass1);
//           4 weight matrices -> wcat bf16 (ws0|wn0|ws1|wn1).
// ---------------------------------------------------------------------------
__global__ __launch_bounds__(256) void convert_kernel(
    const float* __restrict__ x,
    const float* __restrict__ w0, const float* __restrict__ w1,
    const float* __restrict__ w2, const float* __restrict__ w3,
    unsigned short* __restrict__ xb, unsigned short* __restrict__ Bf1,
    unsigned short* __restrict__ wcat)
{
    const int bid = blockIdx.x, t = threadIdx.x;
    if (bid < 128) {
        __shared__ unsigned short XT[128][72];   // [col][local row]
        const int base = bid * 8192;             // 64 rows * 128 cols
        #pragma unroll
        for (int i = 0; i < 32; ++i) {
            int off = i * 256 + t;
            unsigned short b = f2bf(x[base + off]);
            xb[base + off] = b;
            XT[off & 127][off >> 7] = b;
        }
        __syncthreads();
        uint4* dst = (uint4*)Bf1;
        #pragma unroll
        for (int i = 0; i < 4; ++i) {
            int u  = i * 256 + t;
            int sl = u >> 9;                     // local k-step 0/1
            int n  = (u >> 6) & 7;
            int ln = u & 63;
            int col = n * 16 + (ln & 15);
            const uint4* src = (const uint4*)&XT[col][sl * 32 + ((ln >> 4) << 3)];
            dst[((bid * 2 + sl) * 8 + n) * 64 + ln] = *src;
        }
    } else {
        int w = (bid - 128) * 16384 + t;
        #pragma unroll
        for (int i = 0; i < 64; ++i, w += 256) {
            float v;
            if      (w < 32768)  v = w0[w];
            else if (w < 65536)  v = w1[w - 32768];
            else if (w < 98304)  v = w2[w - 65536];
            else                 v = w3[w - 98304];
            wcat[w] = f2bf(v);
        }
    }
}

// ---------------------------------------------------------------------------
// neigh_gemm (x2): C[8192][128] += A_chunk @ B, both operands fragment-linear.
// Split-K=8, grid 1024, 4 waves/block, wave owns 16 rows (mt = m64*4 + w).
// A: 1 contiguous-1KB load/step (depth-3 reg pipeline, 32KB/wave stream).
// B: 8 contiguous loads/step = 8KB (depth-2, L2-hot 256KB/k-chunk).
// ---------------------------------------------------------------------------
__global__ __launch_bounds__(256, 3) void neigh_gemm(
    const unsigned short* __restrict__ Af, const unsigned short* __restrict__ Bf,
    float* __restrict__ C)
{
    const int t = threadIdx.x, lane = t & 63, w = t >> 6, bid = blockIdx.x;
    const int m64 = bid >> 3, kc = bid & 7;
    const int mt  = m64 * 4 + w;

    const uint4* gA = (const uint4*)Af + (size_t)(mt * 8 + kc) * 2048 + lane;
    const uint4* gB = (const uint4*)Bf + (size_t)kc * 16384 + lane;

    f32x4 acc[8];
    #pragma unroll
    for (int n = 0; n < 8; ++n) acc[n] = (f32x4){0.f, 0.f, 0.f, 0.f};

    U4 a[3];
    U4 b[2][8];
    #pragma unroll
    for (int p = 0; p < 3; ++p) a[p].u = gA[p * 64];
    #pragma unroll
    for (int d = 0; d < 2; ++d)
        #pragma unroll
        for (int n = 0; n < 8; ++n) b[d][n].u = gB[d * 512 + n * 64];

    #pragma unroll
    for (int it = 0; it < 32; ++it) {
        U4 af = a[it % 3];
        if (it < 29) a[it % 3].u = gA[(it + 3) * 64];     // A prefetch depth 3
        #pragma unroll
        for (int n = 0; n < 8; ++n)
            acc[n] = mfma16(af.b, b[it & 1][n].b, acc[n]);
        if (it < 30) {                                     // B prefetch depth 2
            #pragma unroll
            for (int n = 0; n < 8; ++n) b[it & 1][n].u = gB[(it + 2) * 512 + n * 64];
        }
    }

    // epilogue: fp32 atomic accumulate (split-K)
    const int col = lane & 15;
    const int r0  = mt * 16 + ((lane >> 4) << 2);
    #pragma unroll
    for (int n = 0; n < 8; ++n)
        #pragma unroll
        for (int r = 0; r < 4; ++r)
            atomicAdd(&C[(r0 + r) * 128 + (n << 4) + col], acc[n][r]);
}

// ---------------------------------------------------------------------------
// Fallback neigh_gemm reading A directly as int32 (if ws too small for Af).
// ---------------------------------------------------------------------------
__global__ __launch_bounds__(256, 4) void neigh_gemm_direct(
    const int* __restrict__ A, const unsigned short* __restrict__ Bf,
    float* __restrict__ C)
{
    const int t = threadIdx.x, lane = t & 63, wave = t >> 6, bid = blockIdx.x;
    const int mbase = (bid >> 3) << 6;
    const int kbase = (bid & 7) << 10;
    const int frow  = mbase + (wave << 4) + (lane & 15);
    const int kslot = (lane >> 4) << 3;

    const int*   gA  = A + frow * 8192 + kbase + kslot;
    const uint4* gBu = (const uint4*)Bf + (kbase >> 5) * 512 + lane;

    f32x4 acc[8];
    #pragma unroll
    for (int n = 0; n < 8; ++n) acc[n] = (f32x4){0.f, 0.f, 0.f, 0.f};

#define CVT_A(af, lo, hi)                                      \
    af.u.x = (unsigned)(lo.x | (lo.y << 16)) * 0x3F80u;        \
    af.u.y = (unsigned)(lo.z | (lo.w << 16)) * 0x3F80u;        \
    af.u.z = (unsigned)(hi.x | (hi.y << 16)) * 0x3F80u;        \
    af.u.w = (unsigned)(hi.z | (hi.w << 16)) * 0x3F80u;

    int4 aLo[3], aHi[3];
    U4 b0[8];
    #pragma unroll
    for (int p = 0; p < 3; ++p) {
        aLo[p] = *(const int4*)(gA + p * 32);
        aHi[p] = *(const int4*)(gA + p * 32 + 4);
    }
    #pragma unroll
    for (int n = 0; n < 8; ++n) b0[n].u = gBu[n * 64];

    #pragma unroll
    for (int it = 0; it < 32; ++it) {
        U4 af; CVT_A(af, aLo[it % 3], aHi[it % 3]);
        if (it < 29) {
            aLo[it % 3] = *(const int4*)(gA + (it + 3) * 32);
            aHi[it % 3] = *(const int4*)(gA + (it + 3) * 32 + 4);
        }
        #pragma unroll
        for (int n = 0; n < 8; ++n) acc[n] = mfma16(af.b, b0[n].b, acc[n]);
        if (it < 31) {
            #pragma unroll
            for (int n = 0; n < 8; ++n) b0[n].u = gBu[(it + 1) * 512 + n * 64];
        }
    }
#undef CVT_A

    const int col = lane & 15;
    const int r0  = mbase + (wave << 4) + ((lane >> 4) << 2);
    #pragma unroll
    for (int n = 0; n < 8; ++n)
        #pragma unroll
        for (int r = 0; r < 4; ++r)
            atomicAdd(&C[(r0 + r) * 128 + (n << 4) + col], acc[n][r]);
}

// ---------------------------------------------------------------------------
// zero_acc: standalone zero kernel for the fallback (non-packed) path.
// ---------------------------------------------------------------------------
__global__ __launch_bounds__(256) void zero_acc(uint4* __restrict__ zbuf)
{
    uint4 z = make_uint4(0, 0, 0, 0);
    uint4* p = zbuf + (size_t)blockIdx.x * 1024 + threadIdx.x;
    p[0] = z; p[256] = z; p[512] = z; p[768] = z;
}

// ---------------------------------------------------------------------------
// h_kernel: h = relu(x@Ws0^T + neigh1@Wn0^T) -> bf16 [8192][256]
// ---------------------------------------------------------------------------
__global__ __launch_bounds__(256) void h_kernel(
    const unsigned short* __restrict__ xb, const float* __restrict__ ng,
    const unsigned short* __restrict__ wcat, unsigned short* __restrict__ h)
{
    const int t = threadIdx.x, lane = t & 63, wave = t >> 6;
    const int wm = wave & 1, wn = wave >> 1;
    const int mbase = blockIdx.x * 32 + wm * 16;
    const int nbase = wn * 128;
    const int row = mbase + (lane & 15);
    const int ko  = (lane >> 4) << 3;

    f32x4 acc[8];
    #pragma unroll
    for (int n = 0; n < 8; ++n) acc[n] = (f32x4){0.f, 0.f, 0.f, 0.f};

    const unsigned short* xl = xb + row * 128 + ko;
    const unsigned short* w0 = wcat + (nbase + (lane & 15)) * 128 + ko;
    #pragma unroll
    for (int ks = 0; ks < 4; ++ks) {
        U4 a; a.u = *(const uint4*)(xl + ks * 32);
        #pragma unroll
        for (int n = 0; n < 8; ++n) {
            U4 b; b.u = *(const uint4*)(w0 + n * (16 * 128) + ks * 32);
            acc[n] = mfma16(a.b, b.b, acc[n]);
        }
    }
    const float* nl = ng + row * 128 + ko;
    const unsigned short* w1 = wcat + 32768 + (nbase + (lane & 15)) * 128 + ko;
    #pragma unroll
    for (int ks = 0; ks < 4; ++ks) {
        float4 f0 = *(const float4*)(nl + ks * 32);
        float4 f1 = *(const float4*)(nl + ks * 32 + 4);
        U4 a;
        a.u.x = (unsigned)f2bf(f0.x) | ((unsigned)f2bf(f0.y) << 16);
        a.u.y = (unsigned)f2bf(f0.z) | ((unsigned)f2bf(f0.w) << 16);
        a.u.z = (unsigned)f2bf(f1.x) | ((unsigned)f2bf(f1.y) << 16);
        a.u.w = (unsigned)f2bf(f1.z) | ((unsigned)f2bf(f1.w) << 16);
        #pragma unroll
        for (int n = 0; n < 8; ++n) {
            U4 b; b.u = *(const uint4*)(w1 + n * (16 * 128) + ks * 32);
            acc[n] = mfma16(a.b, b.b, acc[n]);
        }
    }
    #pragma unroll
    for (int n = 0; n < 8; ++n)
        #pragma unroll
        for (int r = 0; r < 4; ++r) {
            int m = mbase + ((lane >> 4) << 2) + r;
            int c = nbase + (n << 4) + (lane & 15);
            float v = acc[n][r];
            h[m * 256 + c] = f2bf(v > 0.f ? v : 0.f);
        }
}

// ---------------------------------------------------------------------------
// p_kernel: p = h @ Wn1^T, emitted in fragment-linear layout Bf2.
// ---------------------------------------------------------------------------
__global__ __launch_bounds__(256) void p_kernel(
    const unsigned short* __restrict__ h, const unsigned short* __restrict__ wn1,
    unsigned short* __restrict__ Bf2)
{
    __shared__ unsigned short PT[128][48];
    const int t = threadIdx.x, lane = t & 63, wave = t >> 6;
    const int wm = wave & 1, wn = wave >> 1;
    const int mbase = blockIdx.x * 32 + wm * 16;
    const int nbase = wn * 64;
    const int ko = (lane >> 4) << 3;

    f32x4 acc[4];
    #pragma unroll
    for (int n = 0; n < 4; ++n) acc[n] = (f32x4){0.f, 0.f, 0.f, 0.f};

    const unsigned short* hl = h + (mbase + (lane & 15)) * 256 + ko;
    const unsigned short* wl = wn1 + (nbase + (lane & 15)) * 256 + ko;
    #pragma unroll
    for (int ks = 0; ks < 8; ++ks) {
        U4 a; a.u = *(const uint4*)(hl + ks * 32);
        #pragma unroll
        for (int n = 0; n < 4; ++n) {
            U4 b; b.u = *(const uint4*)(wl + n * (16 * 256) + ks * 32);
            acc[n] = mfma16(a.b, b.b, acc[n]);
        }
    }
    const int m0 = wm * 16 + ((lane >> 4) << 2);
    #pragma unroll
    for (int n = 0; n < 4; ++n) {
        int c = nbase + (n << 4) + (lane & 15);
        unsigned int u0 = (unsigned)f2bf(acc[n][0]) | ((unsigned)f2bf(acc[n][1]) << 16);
        unsigned int u1 = (unsigned)f2bf(acc[n][2]) | ((unsigned)f2bf(acc[n][3]) << 16);
        *(uint2*)&PT[c][m0] = make_uint2(u0, u1);
    }
    __syncthreads();
    uint4* dst = (uint4*)Bf2;
    #pragma unroll
    for (int i = 0; i < 2; ++i) {
        int u  = i * 256 + t;
        int n  = u >> 6;
        int ln = u & 63;
        const uint4* src = (const uint4*)&PT[n * 16 + (ln & 15)][(ln >> 4) << 3];
        dst[(blockIdx.x * 8 + n) * 64 + ln] = *src;
    }
}

// ---------------------------------------------------------------------------
// out_kernel: out = relu(h@Ws1^T + tacc) fp32 [8192][128]
// ---------------------------------------------------------------------------
__global__ __launch_bounds__(256) void out_kernel(
    const unsigned short* __restrict__ h, const unsigned short* __restrict__ ws1,
    const float* __restrict__ tacc, float* __restrict__ out)
{
    const int t = threadIdx.x, lane = t & 63, wave = t >> 6;
    const int wm = wave & 1, wn = wave >> 1;
    const int mbase = blockIdx.x * 32 + wm * 16;
    const int nbase = wn * 64;
    const int ko = (lane >> 4) << 3;

    f32x4 acc[4];
    #pragma unroll
    for (int n = 0; n < 4; ++n) acc[n] = (f32x4){0.f, 0.f, 0.f, 0.f};

    const unsigned short* hl = h + (mbase + (lane & 15)) * 256 + ko;
    const unsigned short* wl = ws1 + (nbase + (lane & 15)) * 256 + ko;
    #pragma unroll
    for (int ks = 0; ks < 8; ++ks) {
        U4 a; a.u = *(const uint4*)(hl + ks * 32);
        #pragma unroll
        for (int n = 0; n < 4; ++n) {
            U4 b; b.u = *(const uint4*)(wl + n * (16 * 256) + ks * 32);
            acc[n] = mfma16(a.b, b.b, acc[n]);
        }
    }
    #pragma unroll
    for (int n = 0; n < 4; ++n)
        #pragma unroll
        for (int r = 0; r < 4; ++r) {
            int m = mbase + ((lane >> 4) << 2) + r;
            int c = nbase + (n << 4) + (lane & 15);
            int idx = m * 128 + c;
            float v = acc[n][r] + tacc[idx];
            out[idx] = v > 0.f ? v : 0.f;
        }
}

// ---------------------------------------------------------------------------
extern "C" void kernel_launch(void* const* d_in, const int* in_sizes, int n_in,
                              void* d_out, int out_size, void* d_ws, size_t ws_size,
                              hipStream_t stream)
{
    const float* x   = (const float*)d_in[0];
    const int*   adj = (const int*)d_in[1];
    const float* ws0 = (const float*)d_in[2];
    const float* wn0 = (const float*)d_in[3];
    const float* ws1 = (const float*)d_in[4];
    const float* wn1 = (const float*)d_in[5];
    float* out = (float*)d_out;

    char* ws = (char*)d_ws;
    float*          neigh1 = (float*)(ws);                        // 4 MB
    float*          tacc   = (float*)(ws + (4 << 20));            // 4 MB
    unsigned short* xb     = (unsigned short*)(ws + (8 << 20));   // 2 MB
    unsigned short* Bf1    = (unsigned short*)(ws + (10 << 20));  // 2 MB
    unsigned short* h      = (unsigned short*)(ws + (12 << 20));  // 4 MB
    unsigned short* Bf2    = (unsigned short*)(ws + (16 << 20));  // 2 MB
    unsigned short* wcat   = (unsigned short*)(ws + (18 << 20));  // 256 KB
    unsigned short* Af     = (unsigned short*)(ws + (19 << 20));  // 128 MB

    const bool packed = ws_size >= ((size_t)147 << 20);

    if (packed) {
        // pack_A also zeroes the 8MB split-K accumulator region (blocks >= 4096)
        pack_A<<<4608, 256, 0, stream>>>(adj, Af, (uint4*)ws);
    } else {
        zero_acc<<<512, 256, 0, stream>>>((uint4*)ws);
    }
    convert_kernel<<<136, 256, 0, stream>>>(x, ws0, wn0, ws1, wn1, xb, Bf1, wcat);
    if (packed) neigh_gemm<<<1024, 256, 0, stream>>>(Af, Bf1, neigh1);
    else        neigh_gemm_direct<<<1024, 256, 0, stream>>>(adj, Bf1, neigh1);
    h_kernel<<<256, 256, 0, stream>>>(xb, neigh1, wcat, h);
    p_kernel<<<256, 256, 0, stream>>>(h, wcat + 98304, Bf2);
    if (packed) neigh_gemm<<<1024, 256, 0, stream>>>(Af, Bf2, tacc);
    else        neigh_gemm_direct<<<1024, 256, 0, stream>>>(adj, Bf2, tacc);
    out_kernel<<<256, 256, 0, stream>>>(h, wcat + 65536, tacc, out);
}